// Round 6
// baseline (161.646 us; speedup 1.0000x reference)
//
#include <hip/hip_runtime.h>
#include <math.h>

// Problem constants
#define H   32
#define V   64
#define BB  1024
#define LL  2048
#define NKEY 2047          // keys t=0..2046; seq[...,2047] is the query

// LDS layout (bytes). A1 partials (f32[4][32][64] = 32768 B) alias TGE.
#define OFF_TGE   0        // float2 [64][64]  32768 B  {.x=-G/d, .y=EW}
#define OFF_RTOK  32768    // u8     [4][2048]  8192 B  reversed tokens/batch
#define OFF_ENC   40960    // f32    [64][36]   9216 B  ([v][32]=d_v; 16B-aligned rows)
#define OFF_W     50176    // f32    [32][64]   8192 B  W = read_w @ out_w
#define LDS_TOTAL 58368

// ---------------------------------------------------------------------------
// Exact reformulation (re-derived & re-audited):
//   M_t = M_{t-1} A_t + k_t k_t^T,  A_t = I - k_t k_t^T/d_t  (symmetric)
//   ctx = M_T q = sum_t k_t s_t,  s_t = k_t . z_t,  z_t = A_{t+1}...A_T q
//   z_{t-1} = z_t - (s_t/d_t) k_t  (backward scan, z_T = q)
//   Keys live in 64-token space (k_t = enc[w_t]).  State R[v] = enc_v . z
//   (one float per lane; V == wavefront size):
//     s_t = R[w_t]                        (v_readlane; w_t wave-uniform)
//     R[v] += s_t * (-G[w_t][v]/d_{w_t})  (v_fmac, table row .x)
//     O[o] += s_t * EW[w_t][o]            (v_fmac, table row .y — folded readout)
//   out[o] = B2[o] + O[o];  EW = enc@read_w@out_w;  B2 = read_b@out_w + out_b.
// ---------------------------------------------------------------------------

__device__ __forceinline__ float frdl(float v, int lane) {
    return __int_as_float(__builtin_amdgcn_readlane(__float_as_int(v), lane));
}

struct TPk { int t0,t1,t2,t3,t4,t5,t6,t7; };   // wave-uniform token ids (SGPRs)
struct GPk { float2 p0,p1,p2,p3,p4,p5,p6,p7; };// {g,e} table entries (per lane)

__device__ __forceinline__ void tload(TPk& T, const unsigned char* rt, int base8) {
    const uint2 d = *(const uint2*)(rt + base8);        // ds_read_b64, 8 tokens
    const unsigned lo = (unsigned)__builtin_amdgcn_readfirstlane((int)d.x);
    const unsigned hi = (unsigned)__builtin_amdgcn_readfirstlane((int)d.y);
    T.t0 = lo & 255; T.t1 = (lo >> 8) & 255; T.t2 = (lo >> 16) & 255; T.t3 = lo >> 24;
    T.t4 = hi & 255; T.t5 = (hi >> 8) & 255; T.t6 = (hi >> 16) & 255; T.t7 = hi >> 24;
}

// One guaranteed ds_read_b64 per entry: {−G/d, EW} interleaved.
#define GL1(pk, tk) do { (pk) = *(const float2*)(tgeb + ((tk) << 9) + lane8); } while (0)
__device__ __forceinline__ void gload(GPk& G, const TPk& T,
                                      const char* tgeb, int lane8) {
    GL1(G.p0, T.t0); GL1(G.p1, T.t1); GL1(G.p2, T.t2); GL1(G.p3, T.t3);
    GL1(G.p4, T.t4); GL1(G.p5, T.t5); GL1(G.p6, T.t6); GL1(G.p7, T.t7);
}

#define CH1(pk, tk) do { const float _s = frdl(R, (tk));                    \
                         R = fmaf(_s, (pk).x, R); O = fmaf(_s, (pk).y, O); } while (0)
__device__ __forceinline__ void chain8(const TPk& T, const GPk& G,
                                       float& R, float& O) {
    CH1(G.p0, T.t0); CH1(G.p1, T.t1); CH1(G.p2, T.t2); CH1(G.p3, T.t3);
    CH1(G.p4, T.t4); CH1(G.p5, T.t5); CH1(G.p6, T.t6); CH1(G.p7, T.t7);
}

__global__ __launch_bounds__(256) void fused_kernel(
    const int* __restrict__ seq,
    const float* __restrict__ embed, const float* __restrict__ w1,
    const float* __restrict__ b1,    const float* __restrict__ w2,
    const float* __restrict__ b2,    const float* __restrict__ ln_g,
    const float* __restrict__ ln_b,  const float* __restrict__ read_w,
    const float* __restrict__ read_b,const float* __restrict__ out_w,
    const float* __restrict__ out_b, float* __restrict__ out)
{
    __shared__ __align__(16) char s_mem[LDS_TOTAL];

    const int tid  = threadIdx.x;
    const int lane = tid & 63;
    const int wv   = tid >> 6;          // wave = batch within block
    const int b0   = blockIdx.x * 4;

    // ---- Phase 0: issue this block's seq loads first (hide HBM latency) ----
    int4 pr[8];
#pragma unroll
    for (int u = 0; u < 8; ++u) {
        const int li = u * 256 + tid;                  // 0..2047
        const int r  = li >> 9;                        // batch row 0..3
        const int c4 = li & 511;                       // int4 column
        pr[u] = ((const int4*)(seq + (size_t)(b0 + r) * LL))[c4];
    }
    const int wqv = seq[(size_t)(b0 + wv) * LL + (LL - 1)];   // query token

    // ---- A1: FFN partials, 4 threads/vocab, 16 m's each ----
    {
        const int av = tid >> 2, sb = tid & 3;
        float h[H], xp[H];
#pragma unroll
        for (int j = 0; j < H; ++j) h[j] = embed[av * H + j];
#pragma unroll
        for (int i = 0; i < H; ++i) xp[i] = (sb == 0) ? (h[i] + b2[i]) : 0.0f;
        for (int m = sb * 16; m < sb * 16 + 16; ++m) {
            float z = b1[m];
#pragma unroll
            for (int j = 0; j < H; ++j) z = fmaf(h[j], w1[j * (2 * H) + m], z);
            z = fmaxf(z, 0.0f);
#pragma unroll
            for (int i = 0; i < H; ++i) xp[i] = fmaf(z, w2[m * H + i], xp[i]);
        }
        float* sp = (float*)(s_mem + OFF_TGE);         // alias: [4][32][64]
#pragma unroll
        for (int i = 0; i < H; ++i) sp[(sb * H + i) * V + av] = xp[i];
    }

    // ---- stage reversed u8 tokens (pr regs ready by now) ----
    {
        unsigned char* rt8 = (unsigned char*)(s_mem + OFF_RTOK);
#pragma unroll
        for (int u = 0; u < 8; ++u) {
            const int li = u * 256 + tid;
            const int r  = li >> 9;
            const int c0 = (li & 511) * 4;
            const int vals[4] = {pr[u].x, pr[u].y, pr[u].z, pr[u].w};
#pragma unroll
            for (int m = 0; m < 4; ++m) {
                const int c  = c0 + m;
                const int jj = (c == LL - 1) ? (LL - 1) : (LL - 2 - c);
                rt8[r * LL + jj] = (unsigned char)vals[m];
            }
        }
    }

    // ---- W = read_w @ out_w (wave-split rows) + O init = B2[lane] ----
    float ow[H];
#pragma unroll
    for (int j = 0; j < H; ++j) ow[j] = out_w[j * V + lane];
    float O = out_b[lane];
#pragma unroll
    for (int j = 0; j < H; ++j) O = fmaf(read_b[j], ow[j], O);
    {
        float* sW = (float*)(s_mem + OFF_W);
#pragma unroll
        for (int ii = 0; ii < 8; ++ii) {
            const int i = wv * 8 + ii;
            float acc = 0.0f;
#pragma unroll
            for (int j = 0; j < H; ++j) acc = fmaf(read_w[i * H + j], ow[j], acc);
            sW[i * V + lane] = acc;
        }
    }
    __syncthreads();   // A1 partials + s_W + rtok complete

    // ---- A2: reduce + LayerNorm -> enc (padded rows), d (wave 0 only) ----
    if (tid < V) {
        const int v = tid;
        const float* sp = (const float*)(s_mem + OFF_TGE);
        float x[H], mu = 0.0f;
#pragma unroll
        for (int i = 0; i < H; ++i) {
            x[i] = sp[(0 * H + i) * V + v] + sp[(1 * H + i) * V + v] +
                   sp[(2 * H + i) * V + v] + sp[(3 * H + i) * V + v];
            mu += x[i];
        }
        mu *= (1.0f / H);
        float var = 0.0f;
#pragma unroll
        for (int i = 0; i < H; ++i) { float d0 = x[i] - mu; var = fmaf(d0, d0, var); }
        var *= (1.0f / H);
        const float inv = 1.0f / sqrtf(var + 1e-5f);
        float* se = (float*)(s_mem + OFF_ENC);
        float ss = 0.0f;
#pragma unroll
        for (int i = 0; i < H; ++i) {
            float e = (x[i] - mu) * inv * ln_g[i] + ln_b[i];
            se[v * 36 + i] = e;
            ss = fmaf(e, e, ss);
        }
        se[v * 36 + 32] = ss + 1e-6f;
    }
    __syncthreads();   // enc ready; A1 partials dead -> TGE region writable

    const float* se = (const float*)(s_mem + OFF_ENC);

    // per-lane: er = enc_lane (vectorized), ndv = -1/d_lane, Wr = W[:,lane]
    float er[H];
#pragma unroll
    for (int q = 0; q < 8; ++q) {
        const float4 t = *(const float4*)(se + lane * 36 + q * 4);
        er[q * 4 + 0] = t.x; er[q * 4 + 1] = t.y;
        er[q * 4 + 2] = t.z; er[q * 4 + 3] = t.w;
    }
    const float ndv = -1.0f / se[lane * 36 + 32];
    float Wr[H];
    {
        const float* sW = (const float*)(s_mem + OFF_W);
#pragma unroll
        for (int i = 0; i < H; ++i) Wr[i] = sW[i * V + lane];
    }

    // ---- fused {-G/d, EW} table, wave-split by row; enc_w via uniform
    //      float4 broadcast loads (conflict-free), not readlanes ----
    {
        float2* tge2 = (float2*)(s_mem + OFF_TGE);
        for (int ww = 0; ww < 16; ++ww) {
            const int w = wv * 16 + ww;
            const float4* ew4 = (const float4*)(se + w * 36);
            float aG = 0.0f, aE = 0.0f;
#pragma unroll
            for (int q = 0; q < 8; ++q) {
                const float4 e4 = ew4[q];
                aG = fmaf(e4.x, er[q * 4 + 0], aG); aE = fmaf(e4.x, Wr[q * 4 + 0], aE);
                aG = fmaf(e4.y, er[q * 4 + 1], aG); aE = fmaf(e4.y, Wr[q * 4 + 1], aE);
                aG = fmaf(e4.z, er[q * 4 + 2], aG); aE = fmaf(e4.z, Wr[q * 4 + 2], aE);
                aG = fmaf(e4.w, er[q * 4 + 3], aG); aE = fmaf(e4.w, Wr[q * 4 + 3], aE);
            }
            float2 pr2; pr2.x = aG * frdl(ndv, w); pr2.y = aE;
            tge2[w * V + lane] = pr2;
        }
    }

    // ---- R init: R[lane] = enc_lane . enc_wq  (uniform broadcast loads) ----
    const int wq = __builtin_amdgcn_readfirstlane(wqv);
    float R = 0.0f;
    {
        const float4* q4 = (const float4*)(se + wq * 36);
#pragma unroll
        for (int q = 0; q < 8; ++q) {
            const float4 e4 = q4[q];
            R = fmaf(e4.x, er[q * 4 + 0], R); R = fmaf(e4.y, er[q * 4 + 1], R);
            R = fmaf(e4.z, er[q * 4 + 2], R); R = fmaf(e4.w, er[q * 4 + 3], R);
        }
    }
    __syncthreads();   // TGE ready

    // ---- backward scan: 2047 steps = 255 full 8-packs + 7-step tail ----
    const unsigned char* rt   = (const unsigned char*)(s_mem + OFF_RTOK) + wv * LL;
    const char*          tgeb = (const char*)(s_mem + OFF_TGE);
    const int            lane8 = lane << 3;

    TPk T0, T1, T2, T3, TU;
    GPk G0, G1, G2, G3;
    // Prologue invariant for P=0: T0..T2 = tok(0..2); G0,G1 = rows(0,1).
    tload(T0, rt, 0); tload(T1, rt, 8); tload(T2, rt, 16);
    gload(G0, T0, tgeb, lane8); gload(G1, T1, tgeb, lane8);

    // Tokens prefetched 3 packs ahead (~264 cyc cover), table rows 2 packs
    // ahead (~176 cyc) vs ~120 cyc LDS latency. unroll 1: keep body ~1.4 KB
    // so 63 iterations don't thrash L1I.
#pragma unroll 1
    for (int P = 0; P < 252; P += 4) {
        gload(G2, T2, tgeb, lane8); tload(T3, rt, (P + 3) * 8); chain8(T0, G0, R, O);
        gload(G3, T3, tgeb, lane8); tload(T0, rt, (P + 4) * 8); chain8(T1, G1, R, O);
        gload(G0, T0, tgeb, lane8); tload(T1, rt, (P + 5) * 8); chain8(T2, G2, R, O);
        gload(G1, T1, tgeb, lane8); tload(T2, rt, (P + 6) * 8); chain8(T3, G3, R, O);
    }
    // Exit: T0=tok(252), T1=tok(253), T2=tok(254); G0=row(252), G1=row(253).
    gload(G2, T2, tgeb, lane8); tload(TU, rt, 2040); chain8(T0, G0, R, O); // 252
    gload(G3, TU, tgeb, lane8);                      chain8(T1, G1, R, O); // 253
    chain8(T2, G2, R, O);                                                  // 254
    // Tail: steps 2040..2046 (TU.t7 = query token — not chained).
    CH1(G3.p0, TU.t0); CH1(G3.p1, TU.t1); CH1(G3.p2, TU.t2); CH1(G3.p3, TU.t3);
    CH1(G3.p4, TU.t4); CH1(G3.p5, TU.t5); CH1(G3.p6, TU.t6);

    out[(size_t)(b0 + wv) * V + lane] = O;
}

// ---------------------------------------------------------------------------
extern "C" void kernel_launch(void* const* d_in, const int* in_sizes, int n_in,
                              void* d_out, int out_size, void* d_ws, size_t ws_size,
                              hipStream_t stream)
{
    const int*   seq    = (const int*)  d_in[0];
    const float* embed  = (const float*)d_in[1];
    const float* w1     = (const float*)d_in[2];
    const float* b1     = (const float*)d_in[3];
    const float* w2     = (const float*)d_in[4];
    const float* b2     = (const float*)d_in[5];
    const float* ln_g   = (const float*)d_in[6];
    const float* ln_b   = (const float*)d_in[7];
    const float* read_w = (const float*)d_in[8];
    const float* read_b = (const float*)d_in[9];
    const float* out_w  = (const float*)d_in[10];
    const float* out_b  = (const float*)d_in[11];

    fused_kernel<<<BB / 4, 256, 0, stream>>>(seq, embed, w1, b1, w2, b2,
                                             ln_g, ln_b, read_w, read_b,
                                             out_w, out_b, (float*)d_out);
}